// Round 5
// baseline (279.068 us; speedup 1.0000x reference)
//
#include <hip/hip_runtime.h>
#include <math.h>

// Magnus-0 midpoint propagation of a damped oscillator.
//   out[0] = x0;  out[i+1] = E_i @ out[i],  E_i = expm(dt_i * A(t_mid_i)) (2x2)
// Structure (2 kernels):
//   KA chunk_E: one 64-thread block per 64 steps. Computes E_j (fp64 math,
//      fp32 store) AND TWO 32-step fp64 products via a 5-level shfl_xor
//      butterfly (offsets <32 stay within each 32-lane half).
//   KB propagate: per (32-step chunk, column-pair-group) block. 2048 blocks =
//      8/CU, 32 waves/CU (max occupancy) to keep enough NT writes in flight.
//      CPT=2 fvec2 NT stores (R3: CPT=4/512 blocks regressed +30us).
//      Prefix Q_c via fp64 Kogge-Stone scan in LDS (R4: measured neutral).
// HBM-write-bound: 256 MiB output -> ~42 us floor at ~6.4 TB/s. Most of the
// measured dur is harness re-poison fill (~1 GiB fillBuffer dispatches at
// ~167 us each in rocprof), which we cannot touch.

#define CS    32     // time steps per chunk (KB granularity)
#define TPB   256
#define MAXCH 256    // max 32-step chunks supported (T <= 8193 here)

typedef float fvec2 __attribute__((ext_vector_type(2)));  // nontemporal-store-able

// ---------------- KA: per-step propagators + two 32-step products ----------------
__global__ __launch_bounds__(64) void chunk_E(
        const float* __restrict__ t,
        const float* __restrict__ p_w2,
        const float* __restrict__ p_g0,
        const float* __restrict__ p_gamp,
        const float* __restrict__ p_od,
        float4* __restrict__ E,
        double* __restrict__ M,     // [2*gridDim][4] fp64 32-step products
        int nsteps) {
    const int c = blockIdx.x;                 // 64-step super-chunk
    const int j = c * 64 + threadIdx.x;
    // Identity for lanes past the end (last partial chunk).
    double e00 = 1.0, e01 = 0.0, e10 = 0.0, e11 = 1.0;
    if (j < nsteps) {
        double w2 = (double)p_w2[0], g0 = (double)p_g0[0];
        double gamp = (double)p_gamp[0], od = (double)p_od[0];
        double t0 = (double)t[j], t1 = (double)t[j + 1];
        double dt = t1 - t0;
        double tm = t0 + 0.5 * dt;
        double gamma = g0 * (1.0 + gamp * sin(od * tm));
        // M = [[0, dt], [-w2*dt, -gamma*dt]]
        double m = -0.5 * gamma * dt;            // tr(M)/2
        double delta = m * m - w2 * dt * dt;     // m^2 - det(M)
        double s = sqrt(fabs(delta));
        double ss = fmax(s, 1e-12);
        double f, g;
        if (delta >= 0.0) {
            f = cosh(s); g = sinh(ss) / ss;      // not taken for this regime
        } else {
            double sn, cz;
            sincos(ss, &sn, &cz);                // one transcendental call
            f = cz; g = sn / ss;
        }
        double em = exp(m);
        // N = M - m*I = [[-m, dt], [-w2*dt, m]]
        e00 = em * (f - g * m);
        e01 = em * (g * dt);
        e10 = em * (-g * w2 * dt);
        e11 = em * (f + g * m);
        E[j] = make_float4((float)e00, (float)e01, (float)e10, (float)e11);
    }
    // 5-level butterfly: product of each 32-lane half (later steps on the left).
    #pragma unroll
    for (int k = 0; k < 5; ++k) {
        const int hi = (threadIdx.x >> k) & 1;
        double p00 = __shfl_xor(e00, 1 << k, 64);
        double p01 = __shfl_xor(e01, 1 << k, 64);
        double p10 = __shfl_xor(e10, 1 << k, 64);
        double p11 = __shfl_xor(e11, 1 << k, 64);
        // A = upper-half product, B = lower-half product; new = A*B.
        double a00 = hi ? e00 : p00, a01 = hi ? e01 : p01;
        double a10 = hi ? e10 : p10, a11 = hi ? e11 : p11;
        double b00 = hi ? p00 : e00, b01 = hi ? p01 : e01;
        double b10 = hi ? p10 : e10, b11 = hi ? p11 : e11;
        e00 = a00 * b00 + a01 * b10;
        e01 = a00 * b01 + a01 * b11;
        e10 = a10 * b00 + a11 * b10;
        e11 = a10 * b01 + a11 * b11;
    }
    if ((threadIdx.x & 31) == 0) {
        const int idx = 2 * c + (threadIdx.x >> 5);   // 32-step chunk index
        M[4 * idx + 0] = e00; M[4 * idx + 1] = e01;
        M[4 * idx + 2] = e10; M[4 * idx + 3] = e11;
    }
}

// ---------------- KB: parallel prefix + propagate + write rows ----------------
__global__ __launch_bounds__(TPB) void propagate(
        const float4* __restrict__ E,
        const double* __restrict__ M,
        const float* __restrict__ x0,
        float* __restrict__ out,
        int nsteps, int B, int bgroups, int nch) {
    __shared__ float4 Es[CS];                // 512 B
    __shared__ double Pl[MAXCH][5];          // scan buffer, padded stride (10 KB)
    const int c   = blockIdx.x / bgroups;
    const int bg  = blockIdx.x % bgroups;
    const int tid = threadIdx.x;
    const int j0  = c * CS;
    const int n   = min(CS, nsteps - j0);

    if (tid < n) Es[tid] = E[j0 + tid];
    for (int i = tid; i < 4 * nch; i += TPB)   // stage M_0..M_{nch-1}
        Pl[i >> 2][i & 3] = M[i];
    __syncthreads();

    // Kogge-Stone inclusive scan: Pl[i] <- M_i * M_{i-1} * ... * M_0 (fp64).
    // All threads reach every barrier (guards only on the LDS work).
    double p00 = 0, p01 = 0, p10 = 0, p11 = 0;
    if (tid < nch) {
        p00 = Pl[tid][0]; p01 = Pl[tid][1]; p10 = Pl[tid][2]; p11 = Pl[tid][3];
    }
    for (int d = 1; d < nch; d <<= 1) {
        double b00 = 0, b01 = 0, b10 = 0, b11 = 0;
        const bool act = (tid >= d) && (tid < nch);
        if (act) {
            b00 = Pl[tid - d][0]; b01 = Pl[tid - d][1];
            b10 = Pl[tid - d][2]; b11 = Pl[tid - d][3];
        }
        __syncthreads();                      // all reads of step-k values done
        if (act) {
            double n00 = p00 * b00 + p01 * b10;   // seg[i] <- seg[i] * seg[i-d]
            double n01 = p00 * b01 + p01 * b11;
            double n10 = p10 * b00 + p11 * b10;
            double n11 = p10 * b01 + p11 * b11;
            p00 = n00; p01 = n01; p10 = n10; p11 = n11;
            Pl[tid][0] = p00; Pl[tid][1] = p01; Pl[tid][2] = p10; Pl[tid][3] = p11;
        }
        __syncthreads();                      // step-(k+1) values visible
    }
    // Q_c = exclusive prefix = Pl[c-1] (identity for c == 0).
    float q00, q01, q10, q11;
    if (c == 0) { q00 = 1.f; q01 = 0.f; q10 = 0.f; q11 = 1.f; }
    else {
        q00 = (float)Pl[c - 1][0]; q01 = (float)Pl[c - 1][1];
        q10 = (float)Pl[c - 1][2]; q11 = (float)Pl[c - 1][3];
    }

    const int b = 2 * (bg * TPB + tid);      // two consecutive columns
    if (b >= B) return;                      // no barriers past this point

    const float2 xr0 = *(const float2*)(x0 + b);       // row 0, cols b,b+1
    const float2 xr1 = *(const float2*)(x0 + B + b);   // row 1, cols b,b+1
    float a0 = q00 * xr0.x + q01 * xr1.x;    // x_start = Q_c @ x0
    float c0 = q10 * xr0.x + q11 * xr1.x;
    float a1 = q00 * xr0.y + q01 * xr1.y;
    float c1 = q10 * xr0.y + q11 * xr1.y;

    if (c == 0) {                            // row 0 = x0 verbatim
        fvec2 z0; z0.x = xr0.x; z0.y = xr0.y;
        fvec2 z1; z1.x = xr1.x; z1.y = xr1.y;
        __builtin_nontemporal_store(z0, (fvec2*)(out + b));
        __builtin_nontemporal_store(z1, (fvec2*)(out + B + b));
    }

    float* o = out + (size_t)(j0 + 1) * 2 * (size_t)B + b;
    #pragma unroll 4
    for (int jj = 0; jj < n; ++jj) {
        float4 e = Es[jj];
        float na0 = e.x * a0 + e.y * c0;
        float nc0 = e.z * a0 + e.w * c0;
        float na1 = e.x * a1 + e.y * c1;
        float nc1 = e.z * a1 + e.w * c1;
        a0 = na0; c0 = nc0; a1 = na1; c1 = nc1;
        fvec2 r0; r0.x = a0; r0.y = a1;
        fvec2 r1; r1.x = c0; r1.y = c1;
        __builtin_nontemporal_store(r0, (fvec2*)o);
        __builtin_nontemporal_store(r1, (fvec2*)(o + B));
        o += 2 * B;
    }
}

extern "C" void kernel_launch(void* const* d_in, const int* in_sizes, int n_in,
                              void* d_out, int out_size, void* d_ws, size_t ws_size,
                              hipStream_t stream) {
    const float* t    = (const float*)d_in[0];
    const float* x0   = (const float*)d_in[1];
    const float* w2   = (const float*)d_in[2];
    const float* g0   = (const float*)d_in[3];
    const float* gamp = (const float*)d_in[4];
    const float* od   = (const float*)d_in[5];
    float* out = (float*)d_out;

    const int T = in_sizes[0];
    const int B = in_sizes[1] / 2;
    const int nsteps = T - 1;
    const int nch64 = (nsteps + 63) / 64;              // chunk_E blocks
    const int nch   = (nsteps + CS - 1) / CS;          // 32-step chunks (256)
    const int bgroups = (B + 2 * TPB - 1) / (2 * TPB); // 8 for B=4096

    // Workspace layout: E (nsteps float4) | M (2*nch64 double4)
    float4* E = (float4*)d_ws;
    double* M = (double*)((char*)d_ws + (((size_t)nsteps * 16 + 255) & ~(size_t)255));

    chunk_E<<<nch64, 64, 0, stream>>>(t, w2, g0, gamp, od, E, M, nsteps);
    propagate<<<nch * bgroups, TPB, 0, stream>>>(E, M, x0, out, nsteps, B, bgroups, nch);
}

// Round 6
// 266.784 us; speedup vs baseline: 1.0460x; 1.0460x over previous
//
#include <hip/hip_runtime.h>
#include <math.h>

// Magnus-0 midpoint propagation of a damped oscillator.
//   out[0] = x0;  out[i+1] = E_i @ out[i],  E_i = expm(dt_i * A(t_mid_i)) (2x2)
// Structure (2 kernels):
//   KA chunk_E: one 64-thread block per 64-step chunk. Computes E_j (fp64 math,
//      fp32 store) AND the fp64 chunk product M_c via a 6-level shfl_xor
//      butterfly tree.
//   KB propagate: per (chunk, column-pair-group) block. CPT=2, 1024 blocks —
//      measured grid-shape curve: 512 blk=304.6us, 1024=274.5, 2048=279.1 ->
//      1024 is the optimum; keep it. Prefix Q_c via fp64 Kogge-Stone scan in
//      LDS (measured neutral vs serial). R6 experiment: REGULAR stores
//      (write-back via L2) instead of nontemporal — fills hit 6.4 TB/s on the
//      regular path vs our ~4.7 TB/s NT.
// HBM-write-bound: 256 MiB output -> ~42 us floor at ~6.4 TB/s. Most of the
// measured dur is harness re-poison fill (~1 GiB fillBuffer dispatches at
// ~167 us each in rocprof), which we cannot touch.

#define CS    64     // time steps per chunk
#define TPB   256
#define MAXCH 256    // max chunks supported by KB's scan buffer (T<=16385)

// ---------------- KA: per-chunk propagators + chunk product ----------------
__global__ __launch_bounds__(64) void chunk_E(
        const float* __restrict__ t,
        const float* __restrict__ p_w2,
        const float* __restrict__ p_g0,
        const float* __restrict__ p_gamp,
        const float* __restrict__ p_od,
        float4* __restrict__ E,
        double* __restrict__ M,     // [nch][4] fp64 chunk products
        int nsteps) {
    const int c = blockIdx.x;
    const int j = c * CS + threadIdx.x;
    // Identity for lanes past the end (last partial chunk).
    double e00 = 1.0, e01 = 0.0, e10 = 0.0, e11 = 1.0;
    if (j < nsteps) {
        double w2 = (double)p_w2[0], g0 = (double)p_g0[0];
        double gamp = (double)p_gamp[0], od = (double)p_od[0];
        double t0 = (double)t[j], t1 = (double)t[j + 1];
        double dt = t1 - t0;
        double tm = t0 + 0.5 * dt;
        double gamma = g0 * (1.0 + gamp * sin(od * tm));
        // M = [[0, dt], [-w2*dt, -gamma*dt]]
        double m = -0.5 * gamma * dt;            // tr(M)/2
        double delta = m * m - w2 * dt * dt;     // m^2 - det(M)
        double s = sqrt(fabs(delta));
        double ss = fmax(s, 1e-12);
        double f, g;
        if (delta >= 0.0) {
            f = cosh(s); g = sinh(ss) / ss;      // not taken for this regime
        } else {
            double sn, cz;
            sincos(ss, &sn, &cz);                // one transcendental call
            f = cz; g = sn / ss;
        }
        double em = exp(m);
        // N = M - m*I = [[-m, dt], [-w2*dt, m]]
        e00 = em * (f - g * m);
        e01 = em * (g * dt);
        e10 = em * (-g * w2 * dt);
        e11 = em * (f + g * m);
        E[j] = make_float4((float)e00, (float)e01, (float)e10, (float)e11);
    }
    // Wave-level butterfly tree: after 6 levels every lane holds
    // P = E_{j0+63} * ... * E_{j0}  (later steps on the left).
    #pragma unroll
    for (int k = 0; k < 6; ++k) {
        const int hi = (threadIdx.x >> k) & 1;
        double p00 = __shfl_xor(e00, 1 << k, 64);
        double p01 = __shfl_xor(e01, 1 << k, 64);
        double p10 = __shfl_xor(e10, 1 << k, 64);
        double p11 = __shfl_xor(e11, 1 << k, 64);
        // A = upper-half product, B = lower-half product; new = A*B.
        double a00 = hi ? e00 : p00, a01 = hi ? e01 : p01;
        double a10 = hi ? e10 : p10, a11 = hi ? e11 : p11;
        double b00 = hi ? p00 : e00, b01 = hi ? p01 : e01;
        double b10 = hi ? p10 : e10, b11 = hi ? p11 : e11;
        e00 = a00 * b00 + a01 * b10;
        e01 = a00 * b01 + a01 * b11;
        e10 = a10 * b00 + a11 * b10;
        e11 = a10 * b01 + a11 * b11;
    }
    if (threadIdx.x == 0) {
        M[4 * c + 0] = e00; M[4 * c + 1] = e01;
        M[4 * c + 2] = e10; M[4 * c + 3] = e11;
    }
}

// ---------------- KB: parallel prefix + propagate + write rows ----------------
__global__ __launch_bounds__(TPB) void propagate(
        const float4* __restrict__ E,
        const double* __restrict__ M,
        const float* __restrict__ x0,
        float* __restrict__ out,
        int nsteps, int B, int bgroups, int nch) {
    __shared__ float4 Es[CS];                // 1 KB
    __shared__ double Pl[MAXCH][5];          // scan buffer, padded stride (10 KB)
    const int c   = blockIdx.x / bgroups;
    const int bg  = blockIdx.x % bgroups;
    const int tid = threadIdx.x;
    const int j0  = c * CS;
    const int n   = min(CS, nsteps - j0);

    if (tid < n) Es[tid] = E[j0 + tid];
    for (int i = tid; i < 4 * nch; i += TPB)   // stage M_0..M_{nch-1}
        Pl[i >> 2][i & 3] = M[i];
    __syncthreads();

    // Kogge-Stone inclusive scan: Pl[i] <- M_i * M_{i-1} * ... * M_0 (fp64).
    // All threads reach every barrier (guards only on the LDS work).
    double p00 = 0, p01 = 0, p10 = 0, p11 = 0;
    if (tid < nch) {
        p00 = Pl[tid][0]; p01 = Pl[tid][1]; p10 = Pl[tid][2]; p11 = Pl[tid][3];
    }
    for (int d = 1; d < nch; d <<= 1) {
        double b00 = 0, b01 = 0, b10 = 0, b11 = 0;
        const bool act = (tid >= d) && (tid < nch);
        if (act) {
            b00 = Pl[tid - d][0]; b01 = Pl[tid - d][1];
            b10 = Pl[tid - d][2]; b11 = Pl[tid - d][3];
        }
        __syncthreads();                      // all reads of step-k values done
        if (act) {
            double n00 = p00 * b00 + p01 * b10;   // seg[i] <- seg[i] * seg[i-d]
            double n01 = p00 * b01 + p01 * b11;
            double n10 = p10 * b00 + p11 * b10;
            double n11 = p10 * b01 + p11 * b11;
            p00 = n00; p01 = n01; p10 = n10; p11 = n11;
            Pl[tid][0] = p00; Pl[tid][1] = p01; Pl[tid][2] = p10; Pl[tid][3] = p11;
        }
        __syncthreads();                      // step-(k+1) values visible
    }
    // Q_c = exclusive prefix = Pl[c-1] (identity for c == 0).
    float q00, q01, q10, q11;
    if (c == 0) { q00 = 1.f; q01 = 0.f; q10 = 0.f; q11 = 1.f; }
    else {
        q00 = (float)Pl[c - 1][0]; q01 = (float)Pl[c - 1][1];
        q10 = (float)Pl[c - 1][2]; q11 = (float)Pl[c - 1][3];
    }

    const int b = 2 * (bg * TPB + tid);      // two consecutive columns
    if (b >= B) return;                      // no barriers past this point

    const float2 xr0 = *(const float2*)(x0 + b);       // row 0, cols b,b+1
    const float2 xr1 = *(const float2*)(x0 + B + b);   // row 1, cols b,b+1
    float a0 = q00 * xr0.x + q01 * xr1.x;    // x_start = Q_c @ x0
    float c0 = q10 * xr0.x + q11 * xr1.x;
    float a1 = q00 * xr0.y + q01 * xr1.y;
    float c1 = q10 * xr0.y + q11 * xr1.y;

    if (c == 0) {                            // row 0 = x0 verbatim
        *(float2*)(out + b) = xr0;
        *(float2*)(out + B + b) = xr1;
    }

    float* o = out + (size_t)(j0 + 1) * 2 * (size_t)B + b;
    #pragma unroll 4
    for (int jj = 0; jj < n; ++jj) {
        float4 e = Es[jj];
        float na0 = e.x * a0 + e.y * c0;
        float nc0 = e.z * a0 + e.w * c0;
        float na1 = e.x * a1 + e.y * c1;
        float nc1 = e.z * a1 + e.w * c1;
        a0 = na0; c0 = nc0; a1 = na1; c1 = nc1;
        *(float2*)o       = make_float2(a0, a1);   // regular (write-back) stores
        *(float2*)(o + B) = make_float2(c0, c1);
        o += 2 * B;
    }
}

extern "C" void kernel_launch(void* const* d_in, const int* in_sizes, int n_in,
                              void* d_out, int out_size, void* d_ws, size_t ws_size,
                              hipStream_t stream) {
    const float* t    = (const float*)d_in[0];
    const float* x0   = (const float*)d_in[1];
    const float* w2   = (const float*)d_in[2];
    const float* g0   = (const float*)d_in[3];
    const float* gamp = (const float*)d_in[4];
    const float* od   = (const float*)d_in[5];
    float* out = (float*)d_out;

    const int T = in_sizes[0];
    const int B = in_sizes[1] / 2;
    const int nsteps = T - 1;
    const int nch = (nsteps + CS - 1) / CS;            // 128 for T=8192
    const int bgroups = (B + 2 * TPB - 1) / (2 * TPB); // 8 for B=4096

    // Workspace layout: E (nsteps float4) | M (nch double4)
    float4* E = (float4*)d_ws;
    double* M = (double*)((char*)d_ws + (((size_t)nsteps * 16 + 255) & ~(size_t)255));

    chunk_E<<<nch, 64, 0, stream>>>(t, w2, g0, gamp, od, E, M, nsteps);
    propagate<<<nch * bgroups, TPB, 0, stream>>>(E, M, x0, out, nsteps, B, bgroups, nch);
}